// Round 14
// baseline (545.863 us; speedup 1.0000x reference)
//
#include <hip/hip_runtime.h>
#include <math.h>

#define B    4
#define T    16384
#define A    256
#define K    256
#define PAD  128
#define TP   (T + 2*PAD)      // 16640
#define TOUT (TP - K + 1)     // 16385
#define ITERS 16
#define CHUNK 512
#define NCHUNK 33
#define NCP  36               // (fallback) padded per-atom chunk stride
#define TILE 2048
#define NTILE 9
#define NBLK 512              // grid (both paths)
#define BPB2 128              // blocks per batch (coop path)
#define HBASE 8192            // half split point (outputs & rp base)
#define RPSTORE 8448          // stored rp floats per block (8192 + 256 overlap)
#define RPN 8704              // LDS rp floats incl. zero pad for masked over-reads
#define NGRP 8                // fence-barrier split counters / relay replicas
#define SUBSTRIDE 32          // uints between fence counters (128 B line each)
#define BARSTRIDE (NGRP*SUBSTRIDE)  // uints per batch fence region
#define RSTRIDE 16            // u64s between relay replicas (128 B line each)
#define DLDS 36864            // dynamic LDS request -> 2 blocks/CU
#define TAP(acc, s0,s1,s2,s3, dq) { acc = fmaf(s0,(dq).x,acc); acc = fmaf(s1,(dq).y,acc); \
                                    acc = fmaf(s2,(dq).z,acc); acc = fmaf(s3,(dq).w,acc); }

typedef unsigned long long u64;

__device__ __forceinline__ void wave_amax(float& bv, int& bi) {
    #pragma unroll
    for (int off = 32; off; off >>= 1) {
        float ov = __shfl_down(bv, off);
        int   oi = __shfl_down(bi, off);
        if (ov > bv || (ov == bv && oi < bi)) { bv = ov; bi = oi; }
    }
}

// ===================== LDS-resident HALVES path, leader-relay, VMEM taps =====================
// R13 post-mortem: chunks_update is LDS-BANDWIDTH bound -- per kq it issued
// 5 ds_read_b128 (4 wave-uniform dn-tap broadcasts + 1 rp), and at ~12 cyc/CU
// per b128 the LDS pipe (30.7K cyc/pass/CU) dominates VALU (16K cyc). R14:
// read the taps from GLOBAL dn (uniform address -> single L1-hot 16B fetch on
// the VMEM path), leaving LDS with only the rp read -> pass becomes VALU-bound
// (~6.7us vs 12.8us). Correct without fences: chunks_update reads only the
// block's OWN atoms' rows, self-written in the norm phase (same-block global
// visibility via __syncthreads); cross-block winner-row reads sit behind the
// gen-1 acquire fence. Sync structure = R13 leader-relay (best measured).
struct KSmem {
    float  rp[RPN];           // 34816 B ([8448..8704) zero pad, never written)
    float  chv[4][34];        // per-atom chunk maxima (global chunk ids)
    int    chi[4][34];
    float  wv[16]; int wi[16];
    float  fv; int fi;
    u64    red[2];            // leader 2-wave reduce scratch
};

// Split-counter per-batch barrier -- used ONCE (dn publication fence).
__device__ __forceinline__ void gbar_sub(unsigned* sub, int r, unsigned gen16, int tid) {
    __syncthreads();
    if (tid == 0)
        __hip_atomic_fetch_add(&sub[(r >> 4)*SUBSTRIDE], 1u,
                               __ATOMIC_RELEASE, __HIP_MEMORY_SCOPE_AGENT);
    if (tid < 64) {
        for (;;) {
            unsigned ok = 1;
            if (tid < NGRP)
                ok = (__hip_atomic_load(&sub[tid*SUBSTRIDE], __ATOMIC_RELAXED,
                                        __HIP_MEMORY_SCOPE_AGENT) >= gen16);
            if (__all((int)ok)) break;
            __builtin_amdgcn_s_sleep(4);
        }
    }
    __syncthreads();
    __builtin_amdgcn_fence(__ATOMIC_ACQUIRE, "agent");
}

// Compute conv outputs for up to two 512-chunks (cA -> threads 0..127,
// cB -> threads 128..255; -1 = inactive) for the block's 4 atoms. rp from LDS
// (1 ds_read/kq); taps from global dn via uniform-address loads (VMEM/SMEM
// path, L1-hot -- NOT the LDS pipe). REPLACES chv/chi for the valid chunks.
__device__ void chunks_update(KSmem& sm, int baseF, int cA, int cB, int aBase,
                              const float4* __restrict__ dng4, int tid) {
    const int lane = tid & 63, w = tid >> 6;
    const int grp = tid >> 7;
    const int cg = grp ? cB : cA;
    const int lt = cg*512 + (tid & 127)*4;    // global output t (j=0); cg>=0 only
    float c0[4] = {0,0,0,0}, c1[4] = {0,0,0,0}, c2[4] = {0,0,0,0}, c3[4] = {0,0,0,0};
    if (cg >= 0) {
        const float4* srp4 = (const float4*)sm.rp;
        int ol4 = (lt - baseF) >> 2;
        float4 p = srp4[ol4];
        #pragma unroll 4
        for (int kq = 0; kq < 64; kq++) {
            float4 d0 = dng4[0*64 + kq];      // uniform address -> L1-hot VMEM
            float4 d1 = dng4[1*64 + kq];
            float4 d2 = dng4[2*64 + kq];
            float4 d3 = dng4[3*64 + kq];
            float4 pn = srp4[ol4 + kq + 1];   // the only LDS read per kq
            TAP(c0[0], p.x,p.y,p.z,p.w, d0); TAP(c0[1], p.y,p.z,p.w,pn.x, d0);
            TAP(c0[2], p.z,p.w,pn.x,pn.y, d0); TAP(c0[3], p.w,pn.x,pn.y,pn.z, d0);
            TAP(c1[0], p.x,p.y,p.z,p.w, d1); TAP(c1[1], p.y,p.z,p.w,pn.x, d1);
            TAP(c1[2], p.z,p.w,pn.x,pn.y, d1); TAP(c1[3], p.w,pn.x,pn.y,pn.z, d1);
            TAP(c2[0], p.x,p.y,p.z,p.w, d2); TAP(c2[1], p.y,p.z,p.w,pn.x, d2);
            TAP(c2[2], p.z,p.w,pn.x,pn.y, d2); TAP(c2[3], p.w,pn.x,pn.y,pn.z, d2);
            TAP(c3[0], p.x,p.y,p.z,p.w, d3); TAP(c3[1], p.y,p.z,p.w,pn.x, d3);
            TAP(c3[2], p.z,p.w,pn.x,pn.y, d3); TAP(c3[3], p.w,pn.x,pn.y,pn.z, d3);
            p = pn;
        }
    }
    float bv0 = -INFINITY, bv1 = -INFINITY, bv2 = -INFINITY, bv3 = -INFINITY;
    int bi0 = 0x7fffffff, bi1 = 0x7fffffff, bi2 = 0x7fffffff, bi3 = 0x7fffffff;
    if (cg >= 0) {
        #pragma unroll
        for (int j = 0; j < 4; j++) {
            int t = lt + j;
            if (t < TOUT) {
                if (c0[j] > bv0) { bv0 = c0[j]; bi0 = (aBase+0)*TOUT + t; }
                if (c1[j] > bv1) { bv1 = c1[j]; bi1 = (aBase+1)*TOUT + t; }
                if (c2[j] > bv2) { bv2 = c2[j]; bi2 = (aBase+2)*TOUT + t; }
                if (c3[j] > bv3) { bv3 = c3[j]; bi3 = (aBase+3)*TOUT + t; }
            }
        }
    }
    wave_amax(bv0, bi0); wave_amax(bv1, bi1); wave_amax(bv2, bi2); wave_amax(bv3, bi3);
    if (lane == 0) {
        sm.wv[0*4+w] = bv0; sm.wi[0*4+w] = bi0;
        sm.wv[1*4+w] = bv1; sm.wi[1*4+w] = bi1;
        sm.wv[2*4+w] = bv2; sm.wi[2*4+w] = bi2;
        sm.wv[3*4+w] = bv3; sm.wi[3*4+w] = bi3;
    }
    __syncthreads();
    // combine wave pairs: waves {0,1} -> cA, {2,3} -> cB
    if (tid < 8) {
        int a = tid >> 1, hh = tid & 1;
        int chunk = hh ? cB : cA;
        if (chunk >= 0) {
            float v0 = sm.wv[a*4 + 2*hh];   int i0 = sm.wi[a*4 + 2*hh];
            float v1 = sm.wv[a*4 + 2*hh+1]; int i1 = sm.wi[a*4 + 2*hh+1];
            if (v1 > v0 || (v1 == v0 && i1 < i0)) { v0 = v1; i0 = i1; }
            sm.chv[a][chunk] = v0; sm.chi[a][chunk] = i0;
        }
    }
    __syncthreads();
}

// Block best over 4 atoms x own chunk range -> ONE gen-tagged u64 store.
// Packing: [gen:9][sortable-val:32][0x7FFFFF-idx:23] (R12/R13-verified).
__device__ __forceinline__ void publish(KSmem& sm, u64* slot, int gen, int h, int tid) {
    const int lane = tid & 63, w = tid >> 6;  // wave w -> atom w
    int cstart = h ? 16 : 0, nch = h ? 17 : 16;
    float bv = -INFINITY; int bi = 0x7fffffff;
    if (lane < nch) { bv = sm.chv[w][cstart + lane]; bi = sm.chi[w][cstart + lane]; }
    wave_amax(bv, bi);
    if (lane == 0) { sm.wv[8+w] = bv; sm.wi[8+w] = bi; }
    __syncthreads();
    if (tid == 0) {
        float v = sm.wv[8]; int i = sm.wi[8];
        #pragma unroll
        for (int j = 1; j < 4; j++)
            if (sm.wv[8+j] > v || (sm.wv[8+j] == v && sm.wi[8+j] < i)) { v = sm.wv[8+j]; i = sm.wi[8+j]; }
        unsigned s = __float_as_uint(v);
        unsigned key = (s & 0x80000000u) ? ~s : (s | 0x80000000u);   // sortable float
        u64 e = ((u64)(unsigned)gen << 55) | ((u64)key << 23)
              | (u64)(unsigned)(0x7FFFFF - i);                        // tie -> min idx
        __hip_atomic_store(slot, e, __ATOMIC_RELAXED, __HIP_MEMORY_SCOPE_AGENT);
    }
}

// Leader: lanes 0..127 poll the 128 slots (sole pollers on those lines),
// u64-max reduce, write winner to 8 relay lines, unpack locally.
__device__ __forceinline__ void lead_reduce(KSmem& sm, u64* slotsb, u64* relayb,
                                            int gen, int tid) {
    const int lane = tid & 63, w = tid >> 6;
    if (tid < BPB2) {
        const u64* p = slotsb + tid;
        u64 e;
        for (;;) {
            e = __hip_atomic_load(p, __ATOMIC_RELAXED, __HIP_MEMORY_SCOPE_AGENT);
            if ((unsigned)(e >> 55) == (unsigned)gen) break;
            __builtin_amdgcn_s_sleep(1);
        }
        #pragma unroll
        for (int off = 32; off; off >>= 1) {
            u64 o = __shfl_down(e, off);
            if (o > e) e = o;
        }
        if (lane == 0) sm.red[w] = e;
    }
    __syncthreads();
    if (tid == 0) {
        u64 m = (sm.red[0] > sm.red[1]) ? sm.red[0] : sm.red[1];
        #pragma unroll
        for (int j = 0; j < NGRP; j++)
            __hip_atomic_store(&relayb[j*RSTRIDE], m, __ATOMIC_RELAXED,
                               __HIP_MEMORY_SCOPE_AGENT);
        unsigned key = (unsigned)((m >> 23) & 0xFFFFFFFFull);
        unsigned s = (key & 0x80000000u) ? (key ^ 0x80000000u) : ~key;
        sm.fv = __uint_as_float(s);
        sm.fi = 0x7FFFFF - (int)(m & 0x7FFFFF);
    }
    __syncthreads();
}

// Non-leader: ONE lane polls this block's relay replica (16 pollers/line).
__device__ __forceinline__ void pick_relay(KSmem& sm, const u64* rl, int gen, int tid) {
    if (tid == 0) {
        u64 e;
        for (;;) {
            e = __hip_atomic_load(rl, __ATOMIC_RELAXED, __HIP_MEMORY_SCOPE_AGENT);
            if ((unsigned)(e >> 55) == (unsigned)gen) break;
            __builtin_amdgcn_s_sleep(2);
        }
        unsigned key = (unsigned)((e >> 23) & 0xFFFFFFFFull);
        unsigned s = (key & 0x80000000u) ? (key ^ 0x80000000u) : ~key;
        sm.fv = __uint_as_float(s);
        sm.fi = 0x7FFFFF - (int)(e & 0x7FFFFF);
    }
    __syncthreads();
}

__global__ void __launch_bounds__(256, 2)
k_coop(const float* __restrict__ x, const float* __restrict__ d, float* __restrict__ out,
       float* __restrict__ dn, u64* __restrict__ slots, u64* __restrict__ relay,
       unsigned* __restrict__ fbar) {
    extern __shared__ char raw[];
    KSmem& sm = *(KSmem*)raw;
    const int bid = blockIdx.x, tid = threadIdx.x;
    const int b = bid >> 7, r = bid & 127;
    const int h = r >> 6, a0 = r & 63;       // half, atom-group (4 atoms)
    const int lane = tid & 63, w = tid >> 6;
    const int baseF = h * HBASE;
    const int cstart = h ? 16 : 0, cend = h ? 33 : 16;
    const bool islead = (r == 0);
    const float4* dng4 = (const float4*)(dn + (size_t)(a0*4)*K);  // own 4 rows
    u64* slotsb = slots + (size_t)b*BPB2;    // 128 contiguous slots (8 lines)
    u64* relayb = relay + (size_t)b*NGRP*RSTRIDE;
    unsigned* fbarb = fbar + b*BARSTRIDE;

    // ---- init: x -> LDS rp window (padded domain), zero tail ----
    {
        const float4* x4 = (const float4*)(x + (size_t)b*T);
        float4* rp4w = (float4*)sm.rp;
        int b4 = baseF >> 2;
        for (int i = tid; i < RPN/4; i += 256) {
            int g4 = b4 + i;
            float4 v = {0.f,0.f,0.f,0.f};
            if (i < RPSTORE/4 && g4 >= PAD/4 && g4 < (PAD+T)/4) v = x4[g4 - PAD/4];
            rp4w[i] = v;
        }
    }
    // ---- normalize own 4 atoms -> global dn only (redundant identical writes
    //      across batches; self-reads are same-block visible after barrier;
    //      cross-block reads published by the one full-fence barrier below) ----
    #pragma unroll
    for (int s = 0; s < 4; s++) {
        int atom = a0*4 + s;
        float v = d[atom*K + tid];
        float sq = v*v;
        #pragma unroll
        for (int off = 32; off; off >>= 1) sq += __shfl_down(sq, off);
        if (lane == 0) sm.wv[w] = sq;
        __syncthreads();
        float norm = sqrtf(sm.wv[0] + sm.wv[1] + sm.wv[2] + sm.wv[3]) + 1e-12f;
        dn[atom*K + tid] = v / norm;
        __syncthreads();
    }
    // ---- initial conv over own half (8 or 9 chunk-pair passes) ----
    {
        int npass = h ? 9 : 8;
        for (int p = 0; p < npass; p++) {
            int ca = cstart + 2*p;
            int cb2 = (ca + 1 < cend) ? ca + 1 : -1;
            chunks_update(sm, baseF, ca, cb2, a0*4, dng4, tid);
        }
    }
    int gen = 1;
    publish(sm, slotsb + r, gen, h, tid);
    gbar_sub(fbarb, r, 16u, tid);            // the ONLY full-fence barrier (dn)

    for (int it = 0; it < ITERS-1; it++) {
        if (islead) lead_reduce(sm, slotsb, relayb, gen, tid);
        else        pick_relay(sm, relayb + (r >> 4)*RSTRIDE, gen, tid);
        float val = sm.fv; int idx = sm.fi;
        int atom = idx / TOUT, pos = idx - atom*TOUT;
        float ds = dn[atom*K + tid];            // cross-block row: behind gen-1 fence
        int li = pos + tid - baseF;             // local residual update (if in range)
        if (li >= 0 && li < RPSTORE) sm.rp[li] -= val * ds;
        __syncthreads();
        int lo = pos - (K-1); if (lo < 0) lo = 0;
        int g0 = lo >> 9, g1 = g0 + 1;          // the 2 affected global chunks
        bool in0 = (g0 >= cstart && g0 < cend);
        bool in1 = (g1 >= cstart && g1 < cend);
        int ca = in0 ? g0 : (in1 ? g1 : -1);
        int cb2 = (in0 && in1) ? g1 : -1;
        if (ca >= 0) chunks_update(sm, baseF, ca, cb2, a0*4, dng4, tid);
        publish(sm, slotsb + r, gen+1, h, tid);
        gen++;
        // no separate barrier: slot/relay gen tags ARE the synchronization
    }
    // ---- final pick + update + out (one writer block per (batch, half)) ----
    if (a0 == 0) {
        if (islead) lead_reduce(sm, slotsb, relayb, gen, tid);
        else        pick_relay(sm, relayb + (r >> 4)*RSTRIDE, gen, tid);
        float val = sm.fv; int idx = sm.fi;
        int atom = idx / TOUT, pos = idx - atom*TOUT;
        float ds = dn[atom*K + tid];
        int li = pos + tid - baseF;
        if (li >= 0 && li < RPSTORE) sm.rp[li] -= val * ds;
        __syncthreads();
        // out[b][o] = x[b][o] - rp[o+PAD]; h=0 covers o in [0,8064), h=1 [8064,16384)
        int o_lo4 = h ? (HBASE - PAD)/4 : 0;
        int o_hi4 = h ? T/4 : (HBASE - PAD)/4;
        const float4* xb4 = (const float4*)(x + (size_t)b*T);
        float4* o4 = (float4*)(out + (size_t)b*T);
        for (int i4 = o_lo4 + tid; i4 < o_hi4; i4 += 256) {
            float4 xv = xb4[i4];
            float4 rv = *(const float4*)&sm.rp[i4*4 + PAD - baseF];
            float4 ov; ov.x = xv.x - rv.x; ov.y = xv.y - rv.y;
            ov.z = xv.z - rv.z; ov.w = xv.w - rv.w;
            o4[i4] = ov;
        }
    }
}

// ===================== fallback path (R6, race-free, unchanged) =====================
struct Smem {
    float rp[TILE + K + 16];
    float dnA[K];
    float dnB[K];
    float dnsel[K];
    float wv[16]; int wi[16];
    float fv; int fi;
};

__device__ __forceinline__ void dev_norm(int a0, int tid, const float* __restrict__ d,
                                         float* __restrict__ dn, Smem& sm) {
    int lane = tid & 63, w = tid >> 6;
    #pragma unroll
    for (int s = 0; s < 2; s++) {
        int atom = a0*2 + s;
        float v = d[atom*K + tid];
        float sq = v*v;
        #pragma unroll
        for (int off = 32; off; off >>= 1) sq += __shfl_down(sq, off);
        if (lane == 0) sm.wv[w] = sq;
        __syncthreads();
        float norm = sqrtf(sm.wv[0] + sm.wv[1] + sm.wv[2] + sm.wv[3]) + 1e-12f;
        dn[atom*K + tid] = v / norm;
        __syncthreads();
    }
}

__device__ __forceinline__ void dev_init(int a0, int b, int tid, const float* __restrict__ x,
                                         float* __restrict__ rp, float* __restrict__ recon) {
    int i = a0*256 + tid;
    if (i < TP) {
        float v = (i >= PAD && i < PAD + T) ? x[b*T + (i - PAD)] : 0.f;
        rp[(size_t)b*TP + i] = v;
        recon[(size_t)b*TP + i] = 0.f;
    }
}

__device__ void dev_conv(int a0, int b, int tid, const float* __restrict__ rp,
                         const float* __restrict__ dn,
                         float* __restrict__ segval, int* __restrict__ segidx,
                         float* __restrict__ abv, int* __restrict__ abi, Smem& sm) {
    const int aA = a0*2, aB = a0*2 + 1;
    const int lane = tid & 63, w = tid >> 6;
    sm.dnA[tid] = dn[aA*K + tid];
    sm.dnB[tid] = dn[aB*K + tid];
    const float4* rp4 = (const float4*)(rp + (size_t)b*TP);

    for (int tile = 0; tile < NTILE; tile++) {
        int t0 = tile * TILE;
        __syncthreads();
        float4* s4 = (float4*)sm.rp;
        for (int i = tid; i < 580; i += 256) {
            int g = t0/4 + i;
            float4 v = {0.f,0.f,0.f,0.f};
            if (g*4 < TP) v = rp4[g];
            s4[i] = v;
        }
        __syncthreads();
        const float4* srp4 = (const float4*)sm.rp;
        const float4* dA4  = (const float4*)sm.dnA;
        const float4* dB4  = (const float4*)sm.dnB;
        float accA0[4] = {0,0,0,0}, accA1[4] = {0,0,0,0};
        float accB0[4] = {0,0,0,0}, accB1[4] = {0,0,0,0};
        float4 p = srp4[tid];
        float4 q = srp4[tid + 256];
        #pragma unroll 4
        for (int kq = 0; kq < 64; kq++) {
            float4 dA = dA4[kq];
            float4 dB = dB4[kq];
            float4 pn = srp4[tid + kq + 1];
            float4 qn = srp4[tid + 256 + kq + 1];
            TAP(accA0[0], p.x,p.y,p.z,p.w, dA); TAP(accA0[1], p.y,p.z,p.w,pn.x, dA);
            TAP(accA0[2], p.z,p.w,pn.x,pn.y, dA); TAP(accA0[3], p.w,pn.x,pn.y,pn.z, dA);
            TAP(accB0[0], p.x,p.y,p.z,p.w, dB); TAP(accB0[1], p.y,p.z,p.w,pn.x, dB);
            TAP(accB0[2], p.z,p.w,pn.x,pn.y, dB); TAP(accB0[3], p.w,pn.x,pn.y,pn.z, dB);
            TAP(accA1[0], q.x,q.y,q.z,q.w, dA); TAP(accA1[1], q.y,q.z,q.w,qn.x, dA);
            TAP(accA1[2], q.z,q.w,qn.x,qn.y, dA); TAP(accA1[3], q.w,qn.x,qn.y,qn.z, dA);
            TAP(accB1[0], q.x,q.y,q.z,q.w, dB); TAP(accB1[1], q.y,q.z,q.w,qn.x, dB);
            TAP(accB1[2], q.z,q.w,qn.x,qn.y, dB); TAP(accB1[3], q.w,qn.x,qn.y,qn.z, dB);
            p = pn; q = qn;
        }
        int lt = tid * 4;
        float bvA0 = -INFINITY, bvA1 = -INFINITY, bvB0 = -INFINITY, bvB1 = -INFINITY;
        int biA0 = 0x7fffffff, biA1 = 0x7fffffff, biB0 = 0x7fffffff, biB1 = 0x7fffffff;
        #pragma unroll
        for (int j = 0; j < 4; j++) {
            int t = t0 + lt + j;
            if (t < TOUT) {
                if (accA0[j] > bvA0) { bvA0 = accA0[j]; biA0 = aA*TOUT + t; }
                if (accB0[j] > bvB0) { bvB0 = accB0[j]; biB0 = aB*TOUT + t; }
            }
            int t1 = t0 + 1024 + lt + j;
            if (t1 < TOUT) {
                if (accA1[j] > bvA1) { bvA1 = accA1[j]; biA1 = aA*TOUT + t1; }
                if (accB1[j] > bvB1) { bvB1 = accB1[j]; biB1 = aB*TOUT + t1; }
            }
        }
        wave_amax(bvA0, biA0); wave_amax(bvA1, biA1);
        wave_amax(bvB0, biB0); wave_amax(bvB1, biB1);
        if (lane == 0) {
            sm.wv[w]    = bvA0; sm.wi[w]    = biA0;
            sm.wv[4+w]  = bvA1; sm.wi[4+w]  = biA1;
            sm.wv[8+w]  = bvB0; sm.wi[8+w]  = biB0;
            sm.wv[12+w] = bvB1; sm.wi[12+w] = biB1;
        }
        __syncthreads();
        if (tid < 4) {
            float v0 = sm.wv[2*tid];   int i0 = sm.wi[2*tid];
            float v1 = sm.wv[2*tid+1]; int i1 = sm.wi[2*tid+1];
            if (v1 > v0 || (v1 == v0 && i1 < i0)) { v0 = v1; i0 = i1; }
            int chunk = tile*4 + tid;
            if (chunk < NCHUNK) {
                segval[((size_t)b*A + aA)*NCP + chunk] = v0;
                segidx[((size_t)b*A + aA)*NCP + chunk] = i0;
            }
        } else if (tid >= 64 && tid < 68) {
            int c = tid - 64;
            float v0 = sm.wv[8+2*c];   int i0 = sm.wi[8+2*c];
            float v1 = sm.wv[8+2*c+1]; int i1 = sm.wi[8+2*c+1];
            if (v1 > v0 || (v1 == v0 && i1 < i0)) { v0 = v1; i0 = i1; }
            int chunk = tile*4 + c;
            if (chunk < NCHUNK) {
                segval[((size_t)b*A + aB)*NCP + chunk] = v0;
                segidx[((size_t)b*A + aB)*NCP + chunk] = i0;
            }
        }
    }
    __syncthreads();
    if (w < 2) {
        int atom = (w == 0) ? aA : aB;
        float bv = -INFINITY; int bi = 0x7fffffff;
        if (lane < NCHUNK) {
            bv = segval[((size_t)b*A + atom)*NCP + lane];
            bi = segidx[((size_t)b*A + atom)*NCP + lane];
        }
        wave_amax(bv, bi);
        if (lane == 0) { abv[b*A + atom] = bv; abi[b*A + atom] = bi; }
    }
}

__device__ void dev_iter(int a0, int b, int tid, int last,
                         const float* __restrict__ avc, const int* __restrict__ aic,
                         float* __restrict__ avn, int* __restrict__ ain,
                         const float* __restrict__ rin, float* __restrict__ rout,
                         float* __restrict__ recon, const float* __restrict__ dn,
                         float* __restrict__ segval, int* __restrict__ segidx, Smem& sm) {
    const int aA = a0*2, aB = a0*2 + 1;
    const int lane = tid & 63, w = tid >> 6;

    float bv0 = avc[b*A + tid]; int bi0 = aic[b*A + tid];
    const float4* rin4 = (const float4*)(rin + (size_t)b*TP);
    const int icopy = a0*256 + tid;
    const bool docopy = (!last) && (icopy < TP/4);
    float4 vcopy = {0.f,0.f,0.f,0.f};
    if (docopy) vcopy = rin4[icopy];
    sm.dnA[tid] = dn[aA*K + tid];
    sm.dnB[tid] = dn[aB*K + tid];

    {
        float bv = bv0; int bi = bi0;
        wave_amax(bv, bi);
        if (lane == 0) { sm.wv[w] = bv; sm.wi[w] = bi; }
        __syncthreads();
        if (tid == 0) {
            bv = sm.wv[0]; bi = sm.wi[0];
            for (int j = 1; j < 4; j++)
                if (sm.wv[j] > bv || (sm.wv[j] == bv && sm.wi[j] < bi)) { bv = sm.wv[j]; bi = sm.wi[j]; }
            sm.fv = bv; sm.fi = bi;
        }
        __syncthreads();
    }
    float val = sm.fv; int idx = sm.fi;
    int atom = idx / TOUT, pos = idx - atom*TOUT;
    sm.dnsel[tid] = dn[atom*K + tid];

    int lo = pos - (K-1); if (lo < 0) lo = 0;
    int c_lo = lo >> 9;
    int tbase = c_lo * CHUNK;

    if (!last) {
        float4* s4 = (float4*)sm.rp;
        for (int i = tid; i < 324; i += 256) {
            int g = tbase/4 + i;
            float4 v = {0.f,0.f,0.f,0.f};
            if (g*4 < TP) v = rin4[g];
            s4[i] = v;
        }
    }
    __syncthreads();
    if (docopy) {
        float4* rout4 = (float4*)(rout + (size_t)b*TP);
        float4 v = vcopy;
        int o = icopy*4 - pos;
        if (o > -4 && o < K) {
            if (o+0 >= 0 && o+0 < K) v.x -= val * sm.dnsel[o+0];
            if (o+1 >= 0 && o+1 < K) v.y -= val * sm.dnsel[o+1];
            if (o+2 >= 0 && o+2 < K) v.z -= val * sm.dnsel[o+2];
            if (o+3 >= 0 && o+3 < K) v.w -= val * sm.dnsel[o+3];
        }
        rout4[icopy] = v;
    }
    if (a0 == 0) {
        recon[(size_t)b*TP + pos + tid] += val * sm.dnsel[tid];
    }
    if (last) return;

    sm.rp[pos + tid - tbase] -= val * sm.dnsel[tid];
    __syncthreads();

    const float4* srp4 = (const float4*)sm.rp;
    const float4* dA4  = (const float4*)sm.dnA;
    const float4* dB4  = (const float4*)sm.dnB;
    float cA[4] = {0,0,0,0}, cB[4] = {0,0,0,0};
    float4 p = srp4[tid];
    #pragma unroll 4
    for (int kq = 0; kq < 64; kq++) {
        float4 dA = dA4[kq];
        float4 dB = dB4[kq];
        float4 pn = srp4[tid + kq + 1];
        TAP(cA[0], p.x,p.y,p.z,p.w, dA); TAP(cA[1], p.y,p.z,p.w,pn.x, dA);
        TAP(cA[2], p.z,p.w,pn.x,pn.y, dA); TAP(cA[3], p.w,pn.x,pn.y,pn.z, dA);
        TAP(cB[0], p.x,p.y,p.z,p.w, dB); TAP(cB[1], p.y,p.z,p.w,pn.x, dB);
        TAP(cB[2], p.z,p.w,pn.x,pn.y, dB); TAP(cB[3], p.w,pn.x,pn.y,pn.z, dB);
        p = pn;
    }
    int lt = tid * 4;
    float bvA = -INFINITY, bvB = -INFINITY;
    int biA = 0x7fffffff, biB = 0x7fffffff;
    #pragma unroll
    for (int j = 0; j < 4; j++) {
        int t = tbase + lt + j;
        if (t < TOUT) {
            if (cA[j] > bvA) { bvA = cA[j]; biA = aA*TOUT + t; }
            if (cB[j] > bvB) { bvB = cB[j]; biB = aB*TOUT + t; }
        }
    }
    wave_amax(bvA, biA); wave_amax(bvB, biB);
    if (lane == 0) { sm.wv[w] = bvA; sm.wi[w] = biA; sm.wv[8+w] = bvB; sm.wi[8+w] = biB; }
    __syncthreads();
    if (tid < 2) {
        float v0 = sm.wv[2*tid];   int i0 = sm.wi[2*tid];
        float v1 = sm.wv[2*tid+1]; int i1 = sm.wi[2*tid+1];
        if (v1 > v0 || (v1 == v0 && i1 < i0)) { v0 = v1; i0 = i1; }
        int chunk = c_lo + tid;
        if (chunk < NCHUNK) {
            segval[((size_t)b*A + aA)*NCP + chunk] = v0;
            segidx[((size_t)b*A + aA)*NCP + chunk] = i0;
        }
    } else if (tid >= 64 && tid < 66) {
        int c = tid - 64;
        float v0 = sm.wv[8+2*c];   int i0 = sm.wi[8+2*c];
        float v1 = sm.wv[8+2*c+1]; int i1 = sm.wi[8+2*c+1];
        if (v1 > v0 || (v1 == v0 && i1 < i0)) { v0 = v1; i0 = i1; }
        int chunk = c_lo + c;
        if (chunk < NCHUNK) {
            segval[((size_t)b*A + aB)*NCP + chunk] = v0;
            segidx[((size_t)b*A + aB)*NCP + chunk] = i0;
        }
    }
    __syncthreads();
    if (w < 2) {
        int at = (w == 0) ? aA : aB;
        float bv = -INFINITY; int bi = 0x7fffffff;
        if (lane < NCHUNK) {
            bv = segval[((size_t)b*A + at)*NCP + lane];
            bi = segidx[((size_t)b*A + at)*NCP + lane];
        }
        wave_amax(bv, bi);
        if (lane == 0) { avn[b*A + at] = bv; ain[b*A + at] = bi; }
    }
}

__global__ void __launch_bounds__(256) k_f_norm_init(const float* x, const float* d,
                                                     float* dn, float* rp0, float* recon) {
    __shared__ Smem sm;
    dev_norm(blockIdx.x & 127, threadIdx.x, d, dn, sm);
    dev_init(blockIdx.x & 127, blockIdx.x >> 7, threadIdx.x, x, rp0, recon);
}
__global__ void __launch_bounds__(256, 2) k_f_conv(const float* rp, const float* dn,
                                                   float* segval, int* segidx,
                                                   float* abv, int* abi) {
    __shared__ Smem sm;
    dev_conv(blockIdx.x & 127, blockIdx.x >> 7, threadIdx.x, rp, dn, segval, segidx, abv, abi, sm);
}
__global__ void __launch_bounds__(256, 2) k_f_iter(int last,
                                                   const float* avc, const int* aic,
                                                   float* avn, int* ain,
                                                   const float* rin, float* rout,
                                                   float* recon, const float* dn,
                                                   float* segval, int* segidx) {
    __shared__ Smem sm;
    dev_iter(blockIdx.x & 127, blockIdx.x >> 7, threadIdx.x, last,
             avc, aic, avn, ain, rin, rout, recon, dn, segval, segidx, sm);
}
__global__ void k_f_out(const float* recon, float* out) {
    int i = blockIdx.x * blockDim.x + threadIdx.x;
    if (i >= B*T) return;
    int b = i / T, t = i - b*T;
    out[i] = recon[(size_t)b*TP + PAD + t];
}

extern "C" void kernel_launch(void* const* d_in, const int* in_sizes, int n_in,
                              void* d_out, int out_size, void* d_ws, size_t ws_size,
                              hipStream_t stream) {
    const float* x = (const float*)d_in[0];
    const float* d = (const float*)d_in[1];
    float* out = (float*)d_out;

    float* ws     = (float*)d_ws;
    float* dn     = ws;                                   // A*K
    float* rp0    = dn  + (size_t)A*K;                    // B*TP (fallback)
    float* rp1    = rp0 + (size_t)B*TP;                   // B*TP (fallback)
    float* recon  = rp1 + (size_t)B*TP;                   // B*TP (fallback)
    float* segval = recon + (size_t)B*TP;                 // B*A*NCP (fallback)
    int*   segidx = (int*)(segval + (size_t)B*A*NCP);     // B*A*NCP (fallback)
    float* abv0   = (float*)(segidx + (size_t)B*A*NCP);   // B*2*A (fallback exchange)
    float* abv1   = abv0 + (size_t)B*2*A;
    int*   abi0   = (int*)(abv1 + (size_t)B*2*A);
    int*   abi1   = abi0 + (size_t)B*2*A;
    unsigned* fbar= (unsigned*)(abi1 + (size_t)B*2*A);    // B x NGRP fence counters
    u64*  slots   = (u64*)(fbar + (size_t)B*BARSTRIDE);   // B x BPB2 slots
    u64*  relay   = slots + (size_t)B*BPB2;               // B x NGRP relay replicas

    // Coop-path feasibility: 512 co-resident blocks at DLDS dynamic LDS
    // (2 blocks/CU). Host queries only.
    (void)hipFuncSetAttribute((const void*)k_coop,
                              hipFuncAttributeMaxDynamicSharedMemorySize, DLDS);
    int nb = 0, ncu = 0;
    hipError_t e1 = hipOccupancyMaxActiveBlocksPerMultiprocessor(&nb, (const void*)k_coop,
                                                                 256, DLDS);
    hipError_t e2 = hipDeviceGetAttribute(&ncu, hipDeviceAttributeMultiprocessorCount, 0);
    bool coop = (e1 == hipSuccess && e2 == hipSuccess && nb > 0 && ncu > 0 &&
                 (long)nb * ncu >= NBLK);
    if (coop) {
        // fbar + slots + relay contiguous: one memset (counters 0, tags 0)
        size_t zbytes = (size_t)B*BARSTRIDE*4 + (size_t)B*BPB2*8
                      + (size_t)B*NGRP*RSTRIDE*8;
        (void)hipMemsetAsync(fbar, 0, zbytes, stream);
        hipLaunchKernelGGL(k_coop, dim3(NBLK), dim3(256), DLDS, stream,
                           x, d, out, dn, slots, relay, fbar);
        return;
    }
    // fallback: separate launches, double-buffered (race-free)
    k_f_norm_init<<<NBLK, 256, 0, stream>>>(x, d, dn, rp0, recon);
    k_f_conv<<<NBLK, 256, 0, stream>>>(rp0, dn, segval, segidx, abv0, abi0);
    float* rbuf[2] = {rp0, rp1};
    float* av[2]   = {abv0, abv1};
    int*   ai[2]   = {abi0, abi1};
    for (int it = 0; it < ITERS; it++) {
        k_f_iter<<<NBLK, 256, 0, stream>>>(it == ITERS-1 ? 1 : 0,
                                           av[it & 1], ai[it & 1],
                                           av[(it + 1) & 1], ai[(it + 1) & 1],
                                           rbuf[it & 1], rbuf[(it + 1) & 1],
                                           recon, dn, segval, segidx);
    }
    k_f_out<<<(B*T + 255)/256, 256, 0, stream>>>(recon, out);
}

// Round 15
// 502.016 us; speedup vs baseline: 1.0873x; 1.0873x over previous
//
#include <hip/hip_runtime.h>
#include <math.h>

#define B    4
#define T    16384
#define A    256
#define K    256
#define PAD  128
#define TP   (T + 2*PAD)      // 16640
#define TOUT (TP - K + 1)     // 16385
#define ITERS 16
#define CHUNK 512
#define NCHUNK 33
#define NCP  36               // (fallback) padded per-atom chunk stride
#define TILE 2048
#define NTILE 9
#define NBLK 512              // grid (both paths)
#define BPB2 128              // blocks per batch (coop path)
#define HBASE 8192            // half split point (outputs & rp base)
#define RPSTORE 8448          // stored rp floats per block (8192 + 256 overlap)
#define RPN 8704              // LDS rp floats incl. zero pad for masked over-reads
#define NGRP 8                // fence-barrier split counters / relay replicas
#define SUBSTRIDE 32          // uints between fence counters (128 B line each)
#define BARSTRIDE (NGRP*SUBSTRIDE)  // uints per batch fence region
#define RSTRIDE 16            // u64s between relay replicas (128 B line each)
#define DLDS 40960            // dynamic LDS request -> 2 blocks/CU (80KB/CU)

#define TAP(acc, s0,s1,s2,s3, dq) { acc = fmaf(s0,(dq).x,acc); acc = fmaf(s1,(dq).y,acc); \
                                    acc = fmaf(s2,(dq).z,acc); acc = fmaf(s3,(dq).w,acc); }

typedef unsigned long long u64;

__device__ __forceinline__ void wave_amax(float& bv, int& bi) {
    #pragma unroll
    for (int off = 32; off; off >>= 1) {
        float ov = __shfl_down(bv, off);
        int   oi = __shfl_down(bi, off);
        if (ov > bv || (ov == bv && oi < bi)) { bv = ov; bi = oi; }
    }
}

// ===================== LDS-resident HALVES path, leader-relay (R13 revert) =====================
// R14 falsified the LDS-BW theory: dn-tap LDS reads are uniform-address
// BROADCASTS (no conflict, cheap — SQ_LDS_BANK_CONFLICT identical with them
// removed); moving them to VMEM exposed per-kq load latency at 2 waves/SIMD
// (−47us). This is R13 (best measured, 498.8us) with taps back in LDS, plus
// poll tightening: leader slot-poll spins sleep-free (sole pollers on those
// lines), relay poll sleep 2->1.
struct KSmem {
    float  rp[RPN];           // 34816 B ([8448..8704) zero pad, never written)
    float4 dn4[4][64];        // own 4 atoms' taps, 4096 B (broadcast reads)
    float  chv[4][34];        // per-atom chunk maxima (global chunk ids)
    int    chi[4][34];
    float  wv[16]; int wi[16];
    float  fv; int fi;
    u64    red[2];            // leader 2-wave reduce scratch
};

// Split-counter per-batch barrier -- used ONCE (dn publication fence).
__device__ __forceinline__ void gbar_sub(unsigned* sub, int r, unsigned gen16, int tid) {
    __syncthreads();
    if (tid == 0)
        __hip_atomic_fetch_add(&sub[(r >> 4)*SUBSTRIDE], 1u,
                               __ATOMIC_RELEASE, __HIP_MEMORY_SCOPE_AGENT);
    if (tid < 64) {
        for (;;) {
            unsigned ok = 1;
            if (tid < NGRP)
                ok = (__hip_atomic_load(&sub[tid*SUBSTRIDE], __ATOMIC_RELAXED,
                                        __HIP_MEMORY_SCOPE_AGENT) >= gen16);
            if (__all((int)ok)) break;
            __builtin_amdgcn_s_sleep(4);
        }
    }
    __syncthreads();
    __builtin_amdgcn_fence(__ATOMIC_ACQUIRE, "agent");
}

// Compute conv outputs for up to two 512-chunks (cA -> threads 0..127,
// cB -> threads 128..255; -1 = inactive) for the block's 4 atoms, from LDS rp.
// REPLACES chv/chi entries for the valid chunks. Chunk ids are GLOBAL (0..32).
__device__ void chunks_update(KSmem& sm, int baseF, int cA, int cB, int aBase, int tid) {
    const int lane = tid & 63, w = tid >> 6;
    const int grp = tid >> 7;
    const int cg = grp ? cB : cA;
    const int lt = cg*512 + (tid & 127)*4;    // global output t (j=0); cg>=0 only
    float c0[4] = {0,0,0,0}, c1[4] = {0,0,0,0}, c2[4] = {0,0,0,0}, c3[4] = {0,0,0,0};
    if (cg >= 0) {
        const float4* srp4 = (const float4*)sm.rp;
        int ol4 = (lt - baseF) >> 2;
        float4 p = srp4[ol4];
        #pragma unroll 4
        for (int kq = 0; kq < 64; kq++) {
            float4 d0 = sm.dn4[0][kq];        // uniform-address LDS broadcast (free)
            float4 d1 = sm.dn4[1][kq];
            float4 d2 = sm.dn4[2][kq];
            float4 d3 = sm.dn4[3][kq];
            float4 pn = srp4[ol4 + kq + 1];
            TAP(c0[0], p.x,p.y,p.z,p.w, d0); TAP(c0[1], p.y,p.z,p.w,pn.x, d0);
            TAP(c0[2], p.z,p.w,pn.x,pn.y, d0); TAP(c0[3], p.w,pn.x,pn.y,pn.z, d0);
            TAP(c1[0], p.x,p.y,p.z,p.w, d1); TAP(c1[1], p.y,p.z,p.w,pn.x, d1);
            TAP(c1[2], p.z,p.w,pn.x,pn.y, d1); TAP(c1[3], p.w,pn.x,pn.y,pn.z, d1);
            TAP(c2[0], p.x,p.y,p.z,p.w, d2); TAP(c2[1], p.y,p.z,p.w,pn.x, d2);
            TAP(c2[2], p.z,p.w,pn.x,pn.y, d2); TAP(c2[3], p.w,pn.x,pn.y,pn.z, d2);
            TAP(c3[0], p.x,p.y,p.z,p.w, d3); TAP(c3[1], p.y,p.z,p.w,pn.x, d3);
            TAP(c3[2], p.z,p.w,pn.x,pn.y, d3); TAP(c3[3], p.w,pn.x,pn.y,pn.z, d3);
            p = pn;
        }
    }
    float bv0 = -INFINITY, bv1 = -INFINITY, bv2 = -INFINITY, bv3 = -INFINITY;
    int bi0 = 0x7fffffff, bi1 = 0x7fffffff, bi2 = 0x7fffffff, bi3 = 0x7fffffff;
    if (cg >= 0) {
        #pragma unroll
        for (int j = 0; j < 4; j++) {
            int t = lt + j;
            if (t < TOUT) {
                if (c0[j] > bv0) { bv0 = c0[j]; bi0 = (aBase+0)*TOUT + t; }
                if (c1[j] > bv1) { bv1 = c1[j]; bi1 = (aBase+1)*TOUT + t; }
                if (c2[j] > bv2) { bv2 = c2[j]; bi2 = (aBase+2)*TOUT + t; }
                if (c3[j] > bv3) { bv3 = c3[j]; bi3 = (aBase+3)*TOUT + t; }
            }
        }
    }
    wave_amax(bv0, bi0); wave_amax(bv1, bi1); wave_amax(bv2, bi2); wave_amax(bv3, bi3);
    if (lane == 0) {
        sm.wv[0*4+w] = bv0; sm.wi[0*4+w] = bi0;
        sm.wv[1*4+w] = bv1; sm.wi[1*4+w] = bi1;
        sm.wv[2*4+w] = bv2; sm.wi[2*4+w] = bi2;
        sm.wv[3*4+w] = bv3; sm.wi[3*4+w] = bi3;
    }
    __syncthreads();
    // combine wave pairs: waves {0,1} -> cA, {2,3} -> cB
    if (tid < 8) {
        int a = tid >> 1, hh = tid & 1;
        int chunk = hh ? cB : cA;
        if (chunk >= 0) {
            float v0 = sm.wv[a*4 + 2*hh];   int i0 = sm.wi[a*4 + 2*hh];
            float v1 = sm.wv[a*4 + 2*hh+1]; int i1 = sm.wi[a*4 + 2*hh+1];
            if (v1 > v0 || (v1 == v0 && i1 < i0)) { v0 = v1; i0 = i1; }
            sm.chv[a][chunk] = v0; sm.chi[a][chunk] = i0;
        }
    }
    __syncthreads();
}

// Block best over 4 atoms x own chunk range -> ONE gen-tagged u64 store.
// Packing: [gen:9][sortable-val:32][0x7FFFFF-idx:23] (R12/R13-verified).
__device__ __forceinline__ void publish(KSmem& sm, u64* slot, int gen, int h, int tid) {
    const int lane = tid & 63, w = tid >> 6;  // wave w -> atom w
    int cstart = h ? 16 : 0, nch = h ? 17 : 16;
    float bv = -INFINITY; int bi = 0x7fffffff;
    if (lane < nch) { bv = sm.chv[w][cstart + lane]; bi = sm.chi[w][cstart + lane]; }
    wave_amax(bv, bi);
    if (lane == 0) { sm.wv[8+w] = bv; sm.wi[8+w] = bi; }
    __syncthreads();
    if (tid == 0) {
        float v = sm.wv[8]; int i = sm.wi[8];
        #pragma unroll
        for (int j = 1; j < 4; j++)
            if (sm.wv[8+j] > v || (sm.wv[8+j] == v && sm.wi[8+j] < i)) { v = sm.wv[8+j]; i = sm.wi[8+j]; }
        unsigned s = __float_as_uint(v);
        unsigned key = (s & 0x80000000u) ? ~s : (s | 0x80000000u);   // sortable float
        u64 e = ((u64)(unsigned)gen << 55) | ((u64)key << 23)
              | (u64)(unsigned)(0x7FFFFF - i);                        // tie -> min idx
        __hip_atomic_store(slot, e, __ATOMIC_RELAXED, __HIP_MEMORY_SCOPE_AGENT);
    }
}

// Leader: lanes 0..127 poll the 128 slots (sole pollers on those lines,
// sleep-free tight spin), u64-max reduce, write winner to 8 relay lines.
__device__ __forceinline__ void lead_reduce(KSmem& sm, u64* slotsb, u64* relayb,
                                            int gen, int tid) {
    const int lane = tid & 63, w = tid >> 6;
    if (tid < BPB2) {
        const u64* p = slotsb + tid;
        u64 e;
        for (;;) {
            e = __hip_atomic_load(p, __ATOMIC_RELAXED, __HIP_MEMORY_SCOPE_AGENT);
            if ((unsigned)(e >> 55) == (unsigned)gen) break;
        }
        #pragma unroll
        for (int off = 32; off; off >>= 1) {
            u64 o = __shfl_down(e, off);
            if (o > e) e = o;
        }
        if (lane == 0) sm.red[w] = e;
    }
    __syncthreads();
    if (tid == 0) {
        u64 m = (sm.red[0] > sm.red[1]) ? sm.red[0] : sm.red[1];
        #pragma unroll
        for (int j = 0; j < NGRP; j++)
            __hip_atomic_store(&relayb[j*RSTRIDE], m, __ATOMIC_RELAXED,
                               __HIP_MEMORY_SCOPE_AGENT);
        unsigned key = (unsigned)((m >> 23) & 0xFFFFFFFFull);
        unsigned s = (key & 0x80000000u) ? (key ^ 0x80000000u) : ~key;
        sm.fv = __uint_as_float(s);
        sm.fi = 0x7FFFFF - (int)(m & 0x7FFFFF);
    }
    __syncthreads();
}

// Non-leader: ONE lane polls this block's relay replica (16 pollers/line).
__device__ __forceinline__ void pick_relay(KSmem& sm, const u64* rl, int gen, int tid) {
    if (tid == 0) {
        u64 e;
        for (;;) {
            e = __hip_atomic_load(rl, __ATOMIC_RELAXED, __HIP_MEMORY_SCOPE_AGENT);
            if ((unsigned)(e >> 55) == (unsigned)gen) break;
            __builtin_amdgcn_s_sleep(1);
        }
        unsigned key = (unsigned)((e >> 23) & 0xFFFFFFFFull);
        unsigned s = (key & 0x80000000u) ? (key ^ 0x80000000u) : ~key;
        sm.fv = __uint_as_float(s);
        sm.fi = 0x7FFFFF - (int)(e & 0x7FFFFF);
    }
    __syncthreads();
}

__global__ void __launch_bounds__(256, 2)
k_coop(const float* __restrict__ x, const float* __restrict__ d, float* __restrict__ out,
       float* __restrict__ dn, u64* __restrict__ slots, u64* __restrict__ relay,
       unsigned* __restrict__ fbar) {
    extern __shared__ char raw[];
    KSmem& sm = *(KSmem*)raw;
    const int bid = blockIdx.x, tid = threadIdx.x;
    const int b = bid >> 7, r = bid & 127;
    const int h = r >> 6, a0 = r & 63;       // half, atom-group (4 atoms)
    const int lane = tid & 63, w = tid >> 6;
    const int baseF = h * HBASE;
    const int cstart = h ? 16 : 0, cend = h ? 33 : 16;
    const bool islead = (r == 0);
    u64* slotsb = slots + (size_t)b*BPB2;    // 128 contiguous slots (8 lines)
    u64* relayb = relay + (size_t)b*NGRP*RSTRIDE;
    unsigned* fbarb = fbar + b*BARSTRIDE;

    // ---- init: x -> LDS rp window (padded domain), zero tail ----
    {
        const float4* x4 = (const float4*)(x + (size_t)b*T);
        float4* rp4w = (float4*)sm.rp;
        int b4 = baseF >> 2;
        for (int i = tid; i < RPN/4; i += 256) {
            int g4 = b4 + i;
            float4 v = {0.f,0.f,0.f,0.f};
            if (i < RPSTORE/4 && g4 >= PAD/4 && g4 < (PAD+T)/4) v = x4[g4 - PAD/4];
            rp4w[i] = v;
        }
    }
    // ---- normalize own 4 atoms into LDS + global dn (redundant identical writes;
    //      published by the one full-fence barrier below) ----
    #pragma unroll
    for (int s = 0; s < 4; s++) {
        int atom = a0*4 + s;
        float v = d[atom*K + tid];
        float sq = v*v;
        #pragma unroll
        for (int off = 32; off; off >>= 1) sq += __shfl_down(sq, off);
        if (lane == 0) sm.wv[w] = sq;
        __syncthreads();
        float norm = sqrtf(sm.wv[0] + sm.wv[1] + sm.wv[2] + sm.wv[3]) + 1e-12f;
        float nv = v / norm;
        ((float*)&sm.dn4[s][0])[tid] = nv;
        dn[atom*K + tid] = nv;
        __syncthreads();
    }
    // ---- initial conv over own half (8 or 9 chunk-pair passes) ----
    {
        int npass = h ? 9 : 8;
        for (int p = 0; p < npass; p++) {
            int ca = cstart + 2*p;
            int cb2 = (ca + 1 < cend) ? ca + 1 : -1;
            chunks_update(sm, baseF, ca, cb2, a0*4, tid);
        }
    }
    int gen = 1;
    publish(sm, slotsb + r, gen, h, tid);
    gbar_sub(fbarb, r, 16u, tid);            // the ONLY full-fence barrier (dn)

    for (int it = 0; it < ITERS-1; it++) {
        if (islead) lead_reduce(sm, slotsb, relayb, gen, tid);
        else        pick_relay(sm, relayb + (r >> 4)*RSTRIDE, gen, tid);
        float val = sm.fv; int idx = sm.fi;
        int atom = idx / TOUT, pos = idx - atom*TOUT;
        float ds = dn[atom*K + tid];            // winner row: behind gen-1 fence, L2-hot
        int li = pos + tid - baseF;             // local residual update (if in range)
        if (li >= 0 && li < RPSTORE) sm.rp[li] -= val * ds;
        __syncthreads();
        int lo = pos - (K-1); if (lo < 0) lo = 0;
        int g0 = lo >> 9, g1 = g0 + 1;          // the 2 affected global chunks
        bool in0 = (g0 >= cstart && g0 < cend);
        bool in1 = (g1 >= cstart && g1 < cend);
        int ca = in0 ? g0 : (in1 ? g1 : -1);
        int cb2 = (in0 && in1) ? g1 : -1;
        if (ca >= 0) chunks_update(sm, baseF, ca, cb2, a0*4, tid);
        publish(sm, slotsb + r, gen+1, h, tid);
        gen++;
        // no separate barrier: slot/relay gen tags ARE the synchronization
    }
    // ---- final pick + update + out (one writer block per (batch, half)) ----
    if (a0 == 0) {
        if (islead) lead_reduce(sm, slotsb, relayb, gen, tid);
        else        pick_relay(sm, relayb + (r >> 4)*RSTRIDE, gen, tid);
        float val = sm.fv; int idx = sm.fi;
        int atom = idx / TOUT, pos = idx - atom*TOUT;
        float ds = dn[atom*K + tid];
        int li = pos + tid - baseF;
        if (li >= 0 && li < RPSTORE) sm.rp[li] -= val * ds;
        __syncthreads();
        // out[b][o] = x[b][o] - rp[o+PAD]; h=0 covers o in [0,8064), h=1 [8064,16384)
        int o_lo4 = h ? (HBASE - PAD)/4 : 0;
        int o_hi4 = h ? T/4 : (HBASE - PAD)/4;
        const float4* xb4 = (const float4*)(x + (size_t)b*T);
        float4* o4 = (float4*)(out + (size_t)b*T);
        for (int i4 = o_lo4 + tid; i4 < o_hi4; i4 += 256) {
            float4 xv = xb4[i4];
            float4 rv = *(const float4*)&sm.rp[i4*4 + PAD - baseF];
            float4 ov; ov.x = xv.x - rv.x; ov.y = xv.y - rv.y;
            ov.z = xv.z - rv.z; ov.w = xv.w - rv.w;
            o4[i4] = ov;
        }
    }
}

// ===================== fallback path (R6, race-free, unchanged) =====================
struct Smem {
    float rp[TILE + K + 16];
    float dnA[K];
    float dnB[K];
    float dnsel[K];
    float wv[16]; int wi[16];
    float fv; int fi;
};

__device__ __forceinline__ void dev_norm(int a0, int tid, const float* __restrict__ d,
                                         float* __restrict__ dn, Smem& sm) {
    int lane = tid & 63, w = tid >> 6;
    #pragma unroll
    for (int s = 0; s < 2; s++) {
        int atom = a0*2 + s;
        float v = d[atom*K + tid];
        float sq = v*v;
        #pragma unroll
        for (int off = 32; off; off >>= 1) sq += __shfl_down(sq, off);
        if (lane == 0) sm.wv[w] = sq;
        __syncthreads();
        float norm = sqrtf(sm.wv[0] + sm.wv[1] + sm.wv[2] + sm.wv[3]) + 1e-12f;
        dn[atom*K + tid] = v / norm;
        __syncthreads();
    }
}

__device__ __forceinline__ void dev_init(int a0, int b, int tid, const float* __restrict__ x,
                                         float* __restrict__ rp, float* __restrict__ recon) {
    int i = a0*256 + tid;
    if (i < TP) {
        float v = (i >= PAD && i < PAD + T) ? x[b*T + (i - PAD)] : 0.f;
        rp[(size_t)b*TP + i] = v;
        recon[(size_t)b*TP + i] = 0.f;
    }
}

__device__ void dev_conv(int a0, int b, int tid, const float* __restrict__ rp,
                         const float* __restrict__ dn,
                         float* __restrict__ segval, int* __restrict__ segidx,
                         float* __restrict__ abv, int* __restrict__ abi, Smem& sm) {
    const int aA = a0*2, aB = a0*2 + 1;
    const int lane = tid & 63, w = tid >> 6;
    sm.dnA[tid] = dn[aA*K + tid];
    sm.dnB[tid] = dn[aB*K + tid];
    const float4* rp4 = (const float4*)(rp + (size_t)b*TP);

    for (int tile = 0; tile < NTILE; tile++) {
        int t0 = tile * TILE;
        __syncthreads();
        float4* s4 = (float4*)sm.rp;
        for (int i = tid; i < 580; i += 256) {
            int g = t0/4 + i;
            float4 v = {0.f,0.f,0.f,0.f};
            if (g*4 < TP) v = rp4[g];
            s4[i] = v;
        }
        __syncthreads();
        const float4* srp4 = (const float4*)sm.rp;
        const float4* dA4  = (const float4*)sm.dnA;
        const float4* dB4  = (const float4*)sm.dnB;
        float accA0[4] = {0,0,0,0}, accA1[4] = {0,0,0,0};
        float accB0[4] = {0,0,0,0}, accB1[4] = {0,0,0,0};
        float4 p = srp4[tid];
        float4 q = srp4[tid + 256];
        #pragma unroll 4
        for (int kq = 0; kq < 64; kq++) {
            float4 dA = dA4[kq];
            float4 dB = dB4[kq];
            float4 pn = srp4[tid + kq + 1];
            float4 qn = srp4[tid + 256 + kq + 1];
            TAP(accA0[0], p.x,p.y,p.z,p.w, dA); TAP(accA0[1], p.y,p.z,p.w,pn.x, dA);
            TAP(accA0[2], p.z,p.w,pn.x,pn.y, dA); TAP(accA0[3], p.w,pn.x,pn.y,pn.z, dA);
            TAP(accB0[0], p.x,p.y,p.z,p.w, dB); TAP(accB0[1], p.y,p.z,p.w,pn.x, dB);
            TAP(accB0[2], p.z,p.w,pn.x,pn.y, dB); TAP(accB0[3], p.w,pn.x,pn.y,pn.z, dB);
            TAP(accA1[0], q.x,q.y,q.z,q.w, dA); TAP(accA1[1], q.y,q.z,q.w,qn.x, dA);
            TAP(accA1[2], q.z,q.w,qn.x,qn.y, dA); TAP(accA1[3], q.w,qn.x,qn.y,qn.z, dA);
            TAP(accB1[0], q.x,q.y,q.z,q.w, dB); TAP(accB1[1], q.y,q.z,q.w,qn.x, dB);
            TAP(accB1[2], q.z,q.w,qn.x,qn.y, dB); TAP(accB1[3], q.w,qn.x,qn.y,qn.z, dB);
            p = pn; q = qn;
        }
        int lt = tid * 4;
        float bvA0 = -INFINITY, bvA1 = -INFINITY, bvB0 = -INFINITY, bvB1 = -INFINITY;
        int biA0 = 0x7fffffff, biA1 = 0x7fffffff, biB0 = 0x7fffffff, biB1 = 0x7fffffff;
        #pragma unroll
        for (int j = 0; j < 4; j++) {
            int t = t0 + lt + j;
            if (t < TOUT) {
                if (accA0[j] > bvA0) { bvA0 = accA0[j]; biA0 = aA*TOUT + t; }
                if (accB0[j] > bvB0) { bvB0 = accB0[j]; biB0 = aB*TOUT + t; }
            }
            int t1 = t0 + 1024 + lt + j;
            if (t1 < TOUT) {
                if (accA1[j] > bvA1) { bvA1 = accA1[j]; biA1 = aA*TOUT + t1; }
                if (accB1[j] > bvB1) { bvB1 = accB1[j]; biB1 = aB*TOUT + t1; }
            }
        }
        wave_amax(bvA0, biA0); wave_amax(bvA1, biA1);
        wave_amax(bvB0, biB0); wave_amax(bvB1, biB1);
        if (lane == 0) {
            sm.wv[w]    = bvA0; sm.wi[w]    = biA0;
            sm.wv[4+w]  = bvA1; sm.wi[4+w]  = biA1;
            sm.wv[8+w]  = bvB0; sm.wi[8+w]  = biB0;
            sm.wv[12+w] = bvB1; sm.wi[12+w] = biB1;
        }
        __syncthreads();
        if (tid < 4) {
            float v0 = sm.wv[2*tid];   int i0 = sm.wi[2*tid];
            float v1 = sm.wv[2*tid+1]; int i1 = sm.wi[2*tid+1];
            if (v1 > v0 || (v1 == v0 && i1 < i0)) { v0 = v1; i0 = i1; }
            int chunk = tile*4 + tid;
            if (chunk < NCHUNK) {
                segval[((size_t)b*A + aA)*NCP + chunk] = v0;
                segidx[((size_t)b*A + aA)*NCP + chunk] = i0;
            }
        } else if (tid >= 64 && tid < 68) {
            int c = tid - 64;
            float v0 = sm.wv[8+2*c];   int i0 = sm.wi[8+2*c];
            float v1 = sm.wv[8+2*c+1]; int i1 = sm.wi[8+2*c+1];
            if (v1 > v0 || (v1 == v0 && i1 < i0)) { v0 = v1; i0 = i1; }
            int chunk = tile*4 + c;
            if (chunk < NCHUNK) {
                segval[((size_t)b*A + aB)*NCP + chunk] = v0;
                segidx[((size_t)b*A + aB)*NCP + chunk] = i0;
            }
        }
    }
    __syncthreads();
    if (w < 2) {
        int atom = (w == 0) ? aA : aB;
        float bv = -INFINITY; int bi = 0x7fffffff;
        if (lane < NCHUNK) {
            bv = segval[((size_t)b*A + atom)*NCP + lane];
            bi = segidx[((size_t)b*A + atom)*NCP + lane];
        }
        wave_amax(bv, bi);
        if (lane == 0) { abv[b*A + atom] = bv; abi[b*A + atom] = bi; }
    }
}

__device__ void dev_iter(int a0, int b, int tid, int last,
                         const float* __restrict__ avc, const int* __restrict__ aic,
                         float* __restrict__ avn, int* __restrict__ ain,
                         const float* __restrict__ rin, float* __restrict__ rout,
                         float* __restrict__ recon, const float* __restrict__ dn,
                         float* __restrict__ segval, int* __restrict__ segidx, Smem& sm) {
    const int aA = a0*2, aB = a0*2 + 1;
    const int lane = tid & 63, w = tid >> 6;

    float bv0 = avc[b*A + tid]; int bi0 = aic[b*A + tid];
    const float4* rin4 = (const float4*)(rin + (size_t)b*TP);
    const int icopy = a0*256 + tid;
    const bool docopy = (!last) && (icopy < TP/4);
    float4 vcopy = {0.f,0.f,0.f,0.f};
    if (docopy) vcopy = rin4[icopy];
    sm.dnA[tid] = dn[aA*K + tid];
    sm.dnB[tid] = dn[aB*K + tid];

    {
        float bv = bv0; int bi = bi0;
        wave_amax(bv, bi);
        if (lane == 0) { sm.wv[w] = bv; sm.wi[w] = bi; }
        __syncthreads();
        if (tid == 0) {
            bv = sm.wv[0]; bi = sm.wi[0];
            for (int j = 1; j < 4; j++)
                if (sm.wv[j] > bv || (sm.wv[j] == bv && sm.wi[j] < bi)) { bv = sm.wv[j]; bi = sm.wi[j]; }
            sm.fv = bv; sm.fi = bi;
        }
        __syncthreads();
    }
    float val = sm.fv; int idx = sm.fi;
    int atom = idx / TOUT, pos = idx - atom*TOUT;
    sm.dnsel[tid] = dn[atom*K + tid];

    int lo = pos - (K-1); if (lo < 0) lo = 0;
    int c_lo = lo >> 9;
    int tbase = c_lo * CHUNK;

    if (!last) {
        float4* s4 = (float4*)sm.rp;
        for (int i = tid; i < 324; i += 256) {
            int g = tbase/4 + i;
            float4 v = {0.f,0.f,0.f,0.f};
            if (g*4 < TP) v = rin4[g];
            s4[i] = v;
        }
    }
    __syncthreads();
    if (docopy) {
        float4* rout4 = (float4*)(rout + (size_t)b*TP);
        float4 v = vcopy;
        int o = icopy*4 - pos;
        if (o > -4 && o < K) {
            if (o+0 >= 0 && o+0 < K) v.x -= val * sm.dnsel[o+0];
            if (o+1 >= 0 && o+1 < K) v.y -= val * sm.dnsel[o+1];
            if (o+2 >= 0 && o+2 < K) v.z -= val * sm.dnsel[o+2];
            if (o+3 >= 0 && o+3 < K) v.w -= val * sm.dnsel[o+3];
        }
        rout4[icopy] = v;
    }
    if (a0 == 0) {
        recon[(size_t)b*TP + pos + tid] += val * sm.dnsel[tid];
    }
    if (last) return;

    sm.rp[pos + tid - tbase] -= val * sm.dnsel[tid];
    __syncthreads();

    const float4* srp4 = (const float4*)sm.rp;
    const float4* dA4  = (const float4*)sm.dnA;
    const float4* dB4  = (const float4*)sm.dnB;
    float cA[4] = {0,0,0,0}, cB[4] = {0,0,0,0};
    float4 p = srp4[tid];
    #pragma unroll 4
    for (int kq = 0; kq < 64; kq++) {
        float4 dA = dA4[kq];
        float4 dB = dB4[kq];
        float4 pn = srp4[tid + kq + 1];
        TAP(cA[0], p.x,p.y,p.z,p.w, dA); TAP(cA[1], p.y,p.z,p.w,pn.x, dA);
        TAP(cA[2], p.z,p.w,pn.x,pn.y, dA); TAP(cA[3], p.w,pn.x,pn.y,pn.z, dA);
        TAP(cB[0], p.x,p.y,p.z,p.w, dB); TAP(cB[1], p.y,p.z,p.w,pn.x, dB);
        TAP(cB[2], p.z,p.w,pn.x,pn.y, dB); TAP(cB[3], p.w,pn.x,pn.y,pn.z, dB);
        p = pn;
    }
    int lt = tid * 4;
    float bvA = -INFINITY, bvB = -INFINITY;
    int biA = 0x7fffffff, biB = 0x7fffffff;
    #pragma unroll
    for (int j = 0; j < 4; j++) {
        int t = tbase + lt + j;
        if (t < TOUT) {
            if (cA[j] > bvA) { bvA = cA[j]; biA = aA*TOUT + t; }
            if (cB[j] > bvB) { bvB = cB[j]; biB = aB*TOUT + t; }
        }
    }
    wave_amax(bvA, biA); wave_amax(bvB, biB);
    if (lane == 0) { sm.wv[w] = bvA; sm.wi[w] = biA; sm.wv[8+w] = bvB; sm.wi[8+w] = biB; }
    __syncthreads();
    if (tid < 2) {
        float v0 = sm.wv[2*tid];   int i0 = sm.wi[2*tid];
        float v1 = sm.wv[2*tid+1]; int i1 = sm.wi[2*tid+1];
        if (v1 > v0 || (v1 == v0 && i1 < i0)) { v0 = v1; i0 = i1; }
        int chunk = c_lo + tid;
        if (chunk < NCHUNK) {
            segval[((size_t)b*A + aA)*NCP + chunk] = v0;
            segidx[((size_t)b*A + aA)*NCP + chunk] = i0;
        }
    } else if (tid >= 64 && tid < 66) {
        int c = tid - 64;
        float v0 = sm.wv[8+2*c];   int i0 = sm.wi[8+2*c];
        float v1 = sm.wv[8+2*c+1]; int i1 = sm.wi[8+2*c+1];
        if (v1 > v0 || (v1 == v0 && i1 < i0)) { v0 = v1; i0 = i1; }
        int chunk = c_lo + c;
        if (chunk < NCHUNK) {
            segval[((size_t)b*A + aB)*NCP + chunk] = v0;
            segidx[((size_t)b*A + aB)*NCP + chunk] = i0;
        }
    }
    __syncthreads();
    if (w < 2) {
        int at = (w == 0) ? aA : aB;
        float bv = -INFINITY; int bi = 0x7fffffff;
        if (lane < NCHUNK) {
            bv = segval[((size_t)b*A + at)*NCP + lane];
            bi = segidx[((size_t)b*A + at)*NCP + lane];
        }
        wave_amax(bv, bi);
        if (lane == 0) { avn[b*A + at] = bv; ain[b*A + at] = bi; }
    }
}

__global__ void __launch_bounds__(256) k_f_norm_init(const float* x, const float* d,
                                                     float* dn, float* rp0, float* recon) {
    __shared__ Smem sm;
    dev_norm(blockIdx.x & 127, threadIdx.x, d, dn, sm);
    dev_init(blockIdx.x & 127, blockIdx.x >> 7, threadIdx.x, x, rp0, recon);
}
__global__ void __launch_bounds__(256, 2) k_f_conv(const float* rp, const float* dn,
                                                   float* segval, int* segidx,
                                                   float* abv, int* abi) {
    __shared__ Smem sm;
    dev_conv(blockIdx.x & 127, blockIdx.x >> 7, threadIdx.x, rp, dn, segval, segidx, abv, abi, sm);
}
__global__ void __launch_bounds__(256, 2) k_f_iter(int last,
                                                   const float* avc, const int* aic,
                                                   float* avn, int* ain,
                                                   const float* rin, float* rout,
                                                   float* recon, const float* dn,
                                                   float* segval, int* segidx) {
    __shared__ Smem sm;
    dev_iter(blockIdx.x & 127, blockIdx.x >> 7, threadIdx.x, last,
             avc, aic, avn, ain, rin, rout, recon, dn, segval, segidx, sm);
}
__global__ void k_f_out(const float* recon, float* out) {
    int i = blockIdx.x * blockDim.x + threadIdx.x;
    if (i >= B*T) return;
    int b = i / T, t = i - b*T;
    out[i] = recon[(size_t)b*TP + PAD + t];
}

extern "C" void kernel_launch(void* const* d_in, const int* in_sizes, int n_in,
                              void* d_out, int out_size, void* d_ws, size_t ws_size,
                              hipStream_t stream) {
    const float* x = (const float*)d_in[0];
    const float* d = (const float*)d_in[1];
    float* out = (float*)d_out;

    float* ws     = (float*)d_ws;
    float* dn     = ws;                                   // A*K
    float* rp0    = dn  + (size_t)A*K;                    // B*TP (fallback)
    float* rp1    = rp0 + (size_t)B*TP;                   // B*TP (fallback)
    float* recon  = rp1 + (size_t)B*TP;                   // B*TP (fallback)
    float* segval = recon + (size_t)B*TP;                 // B*A*NCP (fallback)
    int*   segidx = (int*)(segval + (size_t)B*A*NCP);     // B*A*NCP (fallback)
    float* abv0   = (float*)(segidx + (size_t)B*A*NCP);   // B*2*A (fallback exchange)
    float* abv1   = abv0 + (size_t)B*2*A;
    int*   abi0   = (int*)(abv1 + (size_t)B*2*A);
    int*   abi1   = abi0 + (size_t)B*2*A;
    unsigned* fbar= (unsigned*)(abi1 + (size_t)B*2*A);    // B x NGRP fence counters
    u64*  slots   = (u64*)(fbar + (size_t)B*BARSTRIDE);   // B x BPB2 slots
    u64*  relay   = slots + (size_t)B*BPB2;               // B x NGRP relay replicas

    // Coop-path feasibility: 512 co-resident blocks at DLDS dynamic LDS
    // (2 blocks/CU). Host queries only.
    (void)hipFuncSetAttribute((const void*)k_coop,
                              hipFuncAttributeMaxDynamicSharedMemorySize, DLDS);
    int nb = 0, ncu = 0;
    hipError_t e1 = hipOccupancyMaxActiveBlocksPerMultiprocessor(&nb, (const void*)k_coop,
                                                                 256, DLDS);
    hipError_t e2 = hipDeviceGetAttribute(&ncu, hipDeviceAttributeMultiprocessorCount, 0);
    bool coop = (e1 == hipSuccess && e2 == hipSuccess && nb > 0 && ncu > 0 &&
                 (long)nb * ncu >= NBLK);
    if (coop) {
        // fbar + slots + relay contiguous: one memset (counters 0, tags 0)
        size_t zbytes = (size_t)B*BARSTRIDE*4 + (size_t)B*BPB2*8
                      + (size_t)B*NGRP*RSTRIDE*8;
        (void)hipMemsetAsync(fbar, 0, zbytes, stream);
        hipLaunchKernelGGL(k_coop, dim3(NBLK), dim3(256), DLDS, stream,
                           x, d, out, dn, slots, relay, fbar);
        return;
    }
    // fallback: separate launches, double-buffered (race-free)
    k_f_norm_init<<<NBLK, 256, 0, stream>>>(x, d, dn, rp0, recon);
    k_f_conv<<<NBLK, 256, 0, stream>>>(rp0, dn, segval, segidx, abv0, abi0);
    float* rbuf[2] = {rp0, rp1};
    float* av[2]   = {abv0, abv1};
    int*   ai[2]   = {abi0, abi1};
    for (int it = 0; it < ITERS; it++) {
        k_f_iter<<<NBLK, 256, 0, stream>>>(it == ITERS-1 ? 1 : 0,
                                           av[it & 1], ai[it & 1],
                                           av[(it + 1) & 1], ai[(it + 1) & 1],
                                           rbuf[it & 1], rbuf[(it + 1) & 1],
                                           recon, dn, segval, segidx);
    }
    k_f_out<<<(B*T + 255)/256, 256, 0, stream>>>(recon, out);
}